// Round 6
// baseline (330.413 us; speedup 1.0000x reference)
//
#include <hip/hip_runtime.h>

#define DD 128
#define HH 512
#define WW 512
#define NVOX (DD*HH*WW)          // 33554432
#define THRESHV 0.997f
#define KPEAKS 131072
#define PEAK_CAP (1u<<18)        // 262144 peak slots (expect ~63K)
#define NBINS 65536

// peaks all lie in (0.997, 1.0): float bits have constant upper 16 bits
// 0x3F7F -> low 16 bits monotone in value. bin=(~bits)&0xFFFF so ascending
// bin == descending value. Exact-value ties are COMMON (~50K representable
// floats in (0.997,1) vs ~100K candidates) -> tie-fix pass is required.

// ---------------- K0: init scratch (ws is poisoned 0xAA before every call).
// sorted[] no longer needs zeroing: counting sort fills 0..np compactly and
// k_finish bounds by np.
__global__ void k_init(unsigned* counters, unsigned* hist) {
    unsigned t = blockIdx.x * 256u + threadIdx.x;
    if (t < 64) counters[t] = 0u;
    if (t < NBINS) hist[t] = 0u;
}

// ---------------- K1: FUSED stream + verify + centroid.
// Phase A: block streams 8192 voxels (8 float4/thread, branchless mask),
//          candidate indices -> LDS.
// Phase B: THREAD-PER-ROW. n*49 row-tasks over 256 threads; each task is
//          2 independent dwordx4 loads + 7-wide kill/sums; accumulate via
//          LDS float atomics. No serial shuffle-reduce chain (R5's phase B
//          was latency-bound on it: L3-warm replay == HBM-cold time).
__global__ void k_find(const float4* __restrict__ vol4, const float* __restrict__ vol,
                       unsigned* counters, unsigned* hist,
                       unsigned long long* keys, float4* psums) {
    __shared__ unsigned lcnt, pcnt, lbase;
    __shared__ unsigned cidx[512];            // candidate voxel indices
    __shared__ float    cval[512];            // candidate center values
    __shared__ float4   accs[512];            // centroid sums per candidate
    __shared__ unsigned killf[512];           // kill flags (benign races)
    __shared__ unsigned lidx[512];            // surviving candidate ids
    if (threadIdx.x == 0) { lcnt = 0; pcnt = 0; }
    __syncthreads();

    // ---- Phase A: stream
    unsigned base4 = blockIdx.x * 2048u + threadIdx.x;   // float4 units
    float4 v[8];
#pragma unroll
    for (int i = 0; i < 8; i++) v[i] = vol4[base4 + i * 256u];
    unsigned m = 0u;
#pragma unroll
    for (int i = 0; i < 8; i++) {
        m |= (v[i].x > THRESHV ? 1u : 0u) << (4 * i);
        m |= (v[i].y > THRESHV ? 1u : 0u) << (4 * i + 1);
        m |= (v[i].z > THRESHV ? 1u : 0u) << (4 * i + 2);
        m |= (v[i].w > THRESHV ? 1u : 0u) << (4 * i + 3);
    }
    while (m) {
        int b = __ffs(m) - 1;
        m &= m - 1u;
        unsigned f4 = base4 + (unsigned)(b >> 2) * 256u;
        cidx[atomicAdd(&lcnt, 1u) & 511u] = f4 * 4u + (unsigned)(b & 3);
    }
    __syncthreads();

    // ---- Phase B prep: centers (L1/L2-hot: this block just streamed them),
    // accumulators, flags.
    unsigned n = lcnt > 512u ? 512u : lcnt;
    for (unsigned i = threadIdx.x; i < n; i += 256u) {
        cval[i] = vol[cidx[i]];
        accs[i] = make_float4(0.f, 0.f, 0.f, 0.f);
        killf[i] = 0u;
    }
    __syncthreads();

    // ---- Phase B: thread-per-row (49 rows per candidate)
    unsigned ntask = n * 49u;
    for (unsigned t = threadIdx.x; t < ntask; t += 256u) {
        unsigned c = t / 49u;
        unsigned r = t - c * 49u;
        int dz = (int)(r / 7u);
        int dy = (int)(r - (unsigned)dz * 7u);
        unsigned idx = cidx[c];
        float center = cval[c];
        int z = idx >> 18, y = (idx >> 9) & 511, x = idx & 511;
        int nz = z + dz - 3, ny = y + dy - 3;
        if ((unsigned)nz >= DD || (unsigned)ny >= HH) continue;  // zero-pad rows
        size_t rowbase = ((size_t)(unsigned)nz << 18) | ((size_t)(unsigned)ny << 9);
        float rv[7];
        if (x >= 3 && x <= WW - 4) {
            float4 f0 = *(const float4*)(vol + rowbase + (unsigned)(x - 3));
            float4 f1 = *(const float4*)(vol + rowbase + (unsigned)(x + 1));
            rv[0] = f0.x; rv[1] = f0.y; rv[2] = f0.z; rv[3] = f0.w;
            rv[4] = f1.x; rv[5] = f1.y; rv[6] = f1.z;
        } else {
            // x-edge (rare, ~1.2% of candidates): clamped scalar loads
#pragma unroll
            for (int d = 0; d < 7; d++) {
                int nx = x + d - 3;
                bool ok = (unsigned)nx < WW;
                float vv = vol[rowbase + (unsigned)(ok ? nx : x)];
                rv[d] = ok ? vv : 0.f;
            }
        }
        bool kill = false;
        float s0r = 0.f, sxr = 0.f;
#pragma unroll
        for (int d = 0; d < 7; d++) {
            kill |= rv[d] > center;
            s0r += rv[d];
            sxr += rv[d] * (float)(d - 3);
        }
        if (kill) killf[c] = 1u;             // benign race: all writers write 1
        atomicAdd(&accs[c].x, s0r);
        atomicAdd(&accs[c].y, sxr);
        atomicAdd(&accs[c].z, s0r * (float)(dy - 3));
        atomicAdd(&accs[c].w, s0r * (float)(dz - 3));
    }
    __syncthreads();

    // ---- emit survivors
    for (unsigned i = threadIdx.x; i < n; i += 256u) {
        if (!killf[i]) {
            unsigned bits = __float_as_uint(cval[i]);
            atomicAdd(&hist[(~bits) & 0xFFFFu], 1u);
            unsigned li = atomicAdd(&pcnt, 1u);
            lidx[li & 511u] = i;
        }
    }
    __syncthreads();
    if (threadIdx.x == 0) lbase = atomicAdd(&counters[1], pcnt);
    __syncthreads();
    unsigned npk = pcnt > 512u ? 512u : pcnt;
    for (unsigned i = threadIdx.x; i < npk; i += 256u) {
        unsigned p = lbase + i;
        if (p < PEAK_CAP) {
            unsigned c = lidx[i];
            keys[p] = ((unsigned long long)__float_as_uint(cval[c]) << 32) | cidx[c];
            psums[p] = accs[c];
        }
    }
}

// ---------------- K2: exclusive prefix sum over 65536 bins (single block),
// uint4-vectorized loads/stores.
__global__ void k_scan(const unsigned* __restrict__ hist, unsigned* cursor) {
    __shared__ unsigned partial[1024];
    int t = threadIdx.x;
    const uint4* h4 = (const uint4*)(hist + t * 64);
    uint4 loc[16];
#pragma unroll
    for (int i = 0; i < 16; i++) loc[i] = h4[i];
    unsigned s = 0;
#pragma unroll
    for (int i = 0; i < 16; i++) s += loc[i].x + loc[i].y + loc[i].z + loc[i].w;
    partial[t] = s;
    __syncthreads();
    for (int off = 1; off < 1024; off <<= 1) {
        unsigned v = (t >= off) ? partial[t - off] : 0u;
        __syncthreads();
        partial[t] += v;
        __syncthreads();
    }
    unsigned run = (t == 0) ? 0u : partial[t - 1];
    uint4* c4 = (uint4*)(cursor + t * 64);
#pragma unroll
    for (int i = 0; i < 16; i++) {
        uint4 h = loc[i]; uint4 o;
        o.x = run; run += h.x;
        o.y = run; run += h.y;
        o.z = run; run += h.z;
        o.w = run; run += h.w;
        c4[i] = o;
    }
}

// ---------------- K3: scatter keys (+slot payload) into descending-value
// order; rows >= np are exactly the all-zero output rows -> zero them here.
__global__ void k_scatter(const unsigned* __restrict__ counters,
                          const unsigned long long* __restrict__ keys,
                          unsigned* cursor, unsigned long long* sorted,
                          unsigned* sslot,
                          float4* __restrict__ out, float* __restrict__ valid) {
    unsigned np = counters[1]; if (np > PEAK_CAP) np = PEAK_CAP;
    unsigned t = blockIdx.x * 256u + threadIdx.x;
    if (t < np) {
        unsigned long long key = keys[t];
        unsigned bits = (unsigned)(key >> 32);
        unsigned pos = atomicAdd(&cursor[(~bits) & 0xFFFFu], 1u);
        if (pos < PEAK_CAP) { sorted[pos] = key; sslot[pos] = t; }
    } else if (t < KPEAKS) {
        out[t] = make_float4(0.f, 0.f, 0.f, 0.f);
        valid[t] = 0.f;
    }
}

// ---------------- K4: tiefix + output fused. Each scatter position finds its
// tie-corrected row (equal-value runs ordered by ascending voxel idx, per
// lax.top_k) and writes the final output row directly. Bounded by np.
__global__ void k_finish(const unsigned* __restrict__ counters,
                         const unsigned long long* __restrict__ sorted,
                         const unsigned* __restrict__ sslot,
                         const float4* __restrict__ psums,
                         float4* __restrict__ out, float* __restrict__ valid) {
    unsigned np = counters[1]; if (np > PEAK_CAP) np = PEAK_CAP;
    unsigned t = blockIdx.x * 256u + threadIdx.x;
    if (t >= np) return;
    unsigned long long key = sorted[t];
    unsigned bits = (unsigned)(key >> 32);
    unsigned s = t;
    while (s > 0 && (unsigned)(sorted[s - 1] >> 32) == bits) s--;
    unsigned myidx = (unsigned)key;
    unsigned rank = 0, e = s;
    while (e < np) {
        unsigned long long k2 = sorted[e];
        if ((unsigned)(k2 >> 32) != bits) break;
        if ((unsigned)k2 < myidx) rank++;
        e++;
    }
    unsigned row = s + rank;
    if (row >= KPEAKS) return;
    unsigned idx = myidx;
    int z = idx >> 18, y = (idx >> 9) & 511, x = idx & 511;
    float4 ps = psums[sslot[t]];
    float val = __uint_as_float(bits);
    float xloc = ps.y / ps.x, yloc = ps.z / ps.x, zloc = ps.w / ps.x;
    float xr = ((float)x + xloc - (float)(WW - 1) * 0.5f) * 0.1f;
    float yr = ((float)y + yloc - (float)(HH - 1) * 0.5f) * 0.1f;
    float zr = ((float)z + zloc + 0.5f) * 0.02f - 2.0f;
    out[row] = make_float4(xr, yr, zr, val);
    valid[row] = 1.f;
}

extern "C" void kernel_launch(void* const* d_in, const int* in_sizes, int n_in,
                              void* d_out, int out_size, void* d_ws, size_t ws_size,
                              hipStream_t stream) {
    const float* vol = (const float*)d_in[0];
    // d_in[1] = max_peaks scalar (device); fixed at 131072 for this problem.

    char* w = (char*)d_ws;
    unsigned* counters = (unsigned*)w;                                   // 1 KB
    unsigned* hist     = (unsigned*)(w + 1024);                          // 256 KB
    unsigned* cursor   = (unsigned*)(w + 1024 + NBINS * 4);              // 256 KB
    char* w2 = w + 1024 + 2 * NBINS * 4;
    unsigned long long* keys   = (unsigned long long*)w2;                // 2 MB
    unsigned long long* sorted = keys + PEAK_CAP;                        // 2 MB
    unsigned* sslot = (unsigned*)(sorted + PEAK_CAP);                    // 1 MB
    float4*   psums = (float4*)(sslot + PEAK_CAP);                       // 4 MB
    // total ~9.5 MB of ws

    float* out_rows = (float*)d_out;                 // (131072, 4)
    float* valid = out_rows + (size_t)KPEAKS * 4;    // (131072,)

    k_init<<<NBINS / 256, 256, 0, stream>>>(counters, hist);
    k_find<<<NVOX / 8192, 256, 0, stream>>>((const float4*)vol, vol, counters, hist, keys, psums);
    k_scan<<<1, 1024, 0, stream>>>(hist, cursor);
    k_scatter<<<PEAK_CAP / 256, 256, 0, stream>>>(counters, keys, cursor, sorted, sslot,
                                                  (float4*)out_rows, valid);
    k_finish<<<PEAK_CAP / 256, 256, 0, stream>>>(counters, sorted, sslot, psums,
                                                 (float4*)out_rows, valid);
}

// Round 7
// 264.529 us; speedup vs baseline: 1.2491x; 1.2491x over previous
//
#include <hip/hip_runtime.h>

#define DD 128
#define HH 512
#define WW 512
#define NVOX (DD*HH*WW)          // 33554432
#define THRESHV 0.997f
#define KPEAKS 131072
#define PEAK_CAP (1u<<18)        // 262144 peak slots (expect ~63K)
#define NBINS 65536

// peaks all lie in (0.997, 1.0): float bits have constant upper 16 bits
// 0x3F7F -> low 16 bits monotone in value. bin=(~bits)&0xFFFF so ascending
// bin == descending value. Exact-value ties are COMMON -> tie-fix required.

// ---------------- K0: init scratch (ws is poisoned 0xAA before every call).
__global__ void k_init(unsigned* counters, unsigned* hist) {
    unsigned t = blockIdx.x * 1024u + threadIdx.x;
    if (t < 64) counters[t] = 0u;
    if (t < NBINS) hist[t] = 0u;
}

// ---------------- K1: FUSED stream + verify + centroid. 1024 threads/block,
// 1024 blocks (R7: testing whether per-workgroup overhead was the 90us floor
// -- R2..R5 all landed 90-116us across wildly different structures at
// 4096-8192 workgroups, ~10x above per-CU cycle models, L3-warm == cold).
// Phase A: block streams 32768 voxels (8 float4/thread, branchless mask),
//          candidate indices -> LDS.
// Phase B: wave per candidate PAIR (R5 body verbatim): lane l<49 owns row
//          (dz=l/7,dy=l%7) = 2 dwordx4; 4 row-loads of the pair issued
//          before use; center via __shfl(rv[3], 24); shuffle-reduce sums.
__global__ void k_find(const float4* __restrict__ vol4, const float* __restrict__ vol,
                       unsigned* counters, unsigned* hist,
                       unsigned long long* keys, float4* psums) {
    __shared__ unsigned lcnt, pcnt, lbase;
    __shared__ unsigned cidx[1024];           // candidate voxel indices (~98 avg)
    __shared__ unsigned long long lbuf[512];  // surviving peak keys (~62 avg)
    __shared__ float4 sbuf[512];              // surviving peak centroid sums
    if (threadIdx.x == 0) { lcnt = 0; pcnt = 0; }
    __syncthreads();

    // ---- Phase A: stream
    unsigned base4 = blockIdx.x * 8192u + threadIdx.x;   // float4 units
    float4 v[8];
#pragma unroll
    for (int i = 0; i < 8; i++) v[i] = vol4[base4 + i * 1024u];
    unsigned m = 0u;
#pragma unroll
    for (int i = 0; i < 8; i++) {
        m |= (v[i].x > THRESHV ? 1u : 0u) << (4 * i);
        m |= (v[i].y > THRESHV ? 1u : 0u) << (4 * i + 1);
        m |= (v[i].z > THRESHV ? 1u : 0u) << (4 * i + 2);
        m |= (v[i].w > THRESHV ? 1u : 0u) << (4 * i + 3);
    }
    while (m) {
        int b = __ffs(m) - 1;
        m &= m - 1u;
        unsigned f4 = base4 + (unsigned)(b >> 2) * 1024u;
        cidx[atomicAdd(&lcnt, 1u) & 1023u] = f4 * 4u + (unsigned)(b & 3);
    }
    __syncthreads();

    // ---- Phase B: verify, 2 candidates per wave iteration (16 waves)
    unsigned n = lcnt > 1024u ? 1024u : lcnt;
    int lane = threadIdx.x & 63;
    int wv = threadIdx.x >> 6;                 // 0..15
    int dz = lane / 7, dy = lane - dz * 7;     // meaningful for lane<49
    for (unsigned base = (unsigned)wv * 2u; base < n; base += 32u) {
        bool has2 = (base + 1u < n);
        unsigned idxA = cidx[base];
        unsigned idxB = has2 ? cidx[base + 1u] : idxA;
        int zA = idxA >> 18, yA = (idxA >> 9) & 511, xA = idxA & 511;
        int zB = idxB >> 18, yB = (idxB >> 9) & 511, xB = idxB & 511;
        int nzA = zA + dz - 3, nyA = yA + dy - 3;
        int nzB = zB + dz - 3, nyB = yB + dy - 3;
        bool rowokA = (lane < 49) && ((unsigned)nzA < DD) && ((unsigned)nyA < HH);
        bool rowokB = (lane < 49) && ((unsigned)nzB < DD) && ((unsigned)nyB < HH);
        size_t rbA = rowokA ? (((size_t)(unsigned)nzA << 18) | ((size_t)(unsigned)nyA << 9))
                            : (((size_t)zA << 18) | ((size_t)yA << 9));
        size_t rbB = rowokB ? (((size_t)(unsigned)nzB << 18) | ((size_t)(unsigned)nyB << 9))
                            : (((size_t)zB << 18) | ((size_t)yB << 9));
        float rvA[7], rvB[7];
        bool intAB = (xA >= 3) && (xA <= WW - 4) && (xB >= 3) && (xB <= WW - 4);
        if (intAB) {
            float4 fA0 = *(const float4*)(vol + rbA + (unsigned)(xA - 3));
            float4 fA1 = *(const float4*)(vol + rbA + (unsigned)(xA + 1));
            float4 fB0 = *(const float4*)(vol + rbB + (unsigned)(xB - 3));
            float4 fB1 = *(const float4*)(vol + rbB + (unsigned)(xB + 1));
            rvA[0] = fA0.x; rvA[1] = fA0.y; rvA[2] = fA0.z; rvA[3] = fA0.w;
            rvA[4] = fA1.x; rvA[5] = fA1.y; rvA[6] = fA1.z;
            rvB[0] = fB0.x; rvB[1] = fB0.y; rvB[2] = fB0.z; rvB[3] = fB0.w;
            rvB[4] = fB1.x; rvB[5] = fB1.y; rvB[6] = fB1.z;
        } else {
            // rare x-edge path (wave-uniform): clamped scalar loads
#pragma unroll
            for (int d = 0; d < 7; d++) {
                int nxA = xA + d - 3;
                bool okA = (unsigned)nxA < WW;
                float va = vol[rbA + (unsigned)(okA ? nxA : xA)];
                rvA[d] = okA ? va : 0.f;
                int nxB = xB + d - 3;
                bool okB = (unsigned)nxB < WW;
                float vb = vol[rbB + (unsigned)(okB ? nxB : xB)];
                rvB[d] = okB ? vb : 0.f;
            }
        }
        if (!rowokA) {
#pragma unroll
            for (int d = 0; d < 7; d++) rvA[d] = 0.f;
        }
        if (!rowokB) {
#pragma unroll
            for (int d = 0; d < 7; d++) rvB[d] = 0.f;
        }
        float centerA = __shfl(rvA[3], 24);
        float centerB = __shfl(rvB[3], 24);

        // ---- candidate A
        {
            bool kill = false;
            float s0r = 0.f, sxr = 0.f;
#pragma unroll
            for (int d = 0; d < 7; d++) {
                kill |= rvA[d] > centerA;
                s0r += rvA[d];
                sxr += rvA[d] * (float)(d - 3);
            }
            if (!__any(kill)) {
                float s0 = s0r, sx = sxr;
                float sy = s0r * (float)(dy - 3);
                float sz = s0r * (float)(dz - 3);
                for (int off = 32; off; off >>= 1) {
                    s0 += __shfl_down(s0, off);
                    sx += __shfl_down(sx, off);
                    sy += __shfl_down(sy, off);
                    sz += __shfl_down(sz, off);
                }
                if (lane == 0) {
                    unsigned bits = __float_as_uint(centerA);
                    atomicAdd(&hist[(~bits) & 0xFFFFu], 1u);
                    unsigned li = atomicAdd(&pcnt, 1u);
                    if (li < 512u) {
                        lbuf[li] = ((unsigned long long)bits << 32) | idxA;
                        sbuf[li] = make_float4(s0, sx, sy, sz);
                    }
                }
            }
        }
        // ---- candidate B
        if (has2) {
            bool kill = false;
            float s0r = 0.f, sxr = 0.f;
#pragma unroll
            for (int d = 0; d < 7; d++) {
                kill |= rvB[d] > centerB;
                s0r += rvB[d];
                sxr += rvB[d] * (float)(d - 3);
            }
            if (!__any(kill)) {
                float s0 = s0r, sx = sxr;
                float sy = s0r * (float)(dy - 3);
                float sz = s0r * (float)(dz - 3);
                for (int off = 32; off; off >>= 1) {
                    s0 += __shfl_down(s0, off);
                    sx += __shfl_down(sx, off);
                    sy += __shfl_down(sy, off);
                    sz += __shfl_down(sz, off);
                }
                if (lane == 0) {
                    unsigned bits = __float_as_uint(centerB);
                    atomicAdd(&hist[(~bits) & 0xFFFFu], 1u);
                    unsigned li = atomicAdd(&pcnt, 1u);
                    if (li < 512u) {
                        lbuf[li] = ((unsigned long long)bits << 32) | idxB;
                        sbuf[li] = make_float4(s0, sx, sy, sz);
                    }
                }
            }
        }
    }
    __syncthreads();
    if (threadIdx.x == 0) lbase = atomicAdd(&counters[1], pcnt);
    __syncthreads();
    unsigned np = pcnt > 512u ? 512u : pcnt;
    for (unsigned i = threadIdx.x; i < np; i += 1024u) {
        unsigned p = lbase + i;
        if (p < PEAK_CAP) { keys[p] = lbuf[i]; psums[p] = sbuf[i]; }
    }
}

// ---------------- K2: exclusive prefix sum over 65536 bins (single block),
// uint4-vectorized loads/stores.
__global__ void k_scan(const unsigned* __restrict__ hist, unsigned* cursor) {
    __shared__ unsigned partial[1024];
    int t = threadIdx.x;
    const uint4* h4 = (const uint4*)(hist + t * 64);
    uint4 loc[16];
#pragma unroll
    for (int i = 0; i < 16; i++) loc[i] = h4[i];
    unsigned s = 0;
#pragma unroll
    for (int i = 0; i < 16; i++) s += loc[i].x + loc[i].y + loc[i].z + loc[i].w;
    partial[t] = s;
    __syncthreads();
    for (int off = 1; off < 1024; off <<= 1) {
        unsigned v = (t >= off) ? partial[t - off] : 0u;
        __syncthreads();
        partial[t] += v;
        __syncthreads();
    }
    unsigned run = (t == 0) ? 0u : partial[t - 1];
    uint4* c4 = (uint4*)(cursor + t * 64);
#pragma unroll
    for (int i = 0; i < 16; i++) {
        uint4 h = loc[i]; uint4 o;
        o.x = run; run += h.x;
        o.y = run; run += h.y;
        o.z = run; run += h.z;
        o.w = run; run += h.w;
        c4[i] = o;
    }
}

// ---------------- K3: scatter keys (+slot payload) into descending-value
// order; rows >= np are exactly the all-zero output rows -> zero them here.
__global__ void k_scatter(const unsigned* __restrict__ counters,
                          const unsigned long long* __restrict__ keys,
                          unsigned* cursor, unsigned long long* sorted,
                          unsigned* sslot,
                          float4* __restrict__ out, float* __restrict__ valid) {
    unsigned np = counters[1]; if (np > PEAK_CAP) np = PEAK_CAP;
    unsigned t = blockIdx.x * 1024u + threadIdx.x;
    if (t < np) {
        unsigned long long key = keys[t];
        unsigned bits = (unsigned)(key >> 32);
        unsigned pos = atomicAdd(&cursor[(~bits) & 0xFFFFu], 1u);
        if (pos < PEAK_CAP) { sorted[pos] = key; sslot[pos] = t; }
    } else if (t < KPEAKS) {
        out[t] = make_float4(0.f, 0.f, 0.f, 0.f);
        valid[t] = 0.f;
    }
}

// ---------------- K4: tiefix + output fused. Each scatter position finds its
// tie-corrected row (equal-value runs ordered by ascending voxel idx, per
// lax.top_k) and writes the final output row directly. Bounded by np.
__global__ void k_finish(const unsigned* __restrict__ counters,
                         const unsigned long long* __restrict__ sorted,
                         const unsigned* __restrict__ sslot,
                         const float4* __restrict__ psums,
                         float4* __restrict__ out, float* __restrict__ valid) {
    unsigned np = counters[1]; if (np > PEAK_CAP) np = PEAK_CAP;
    unsigned t = blockIdx.x * 1024u + threadIdx.x;
    if (t >= np) return;
    unsigned long long key = sorted[t];
    unsigned bits = (unsigned)(key >> 32);
    unsigned s = t;
    while (s > 0 && (unsigned)(sorted[s - 1] >> 32) == bits) s--;
    unsigned myidx = (unsigned)key;
    unsigned rank = 0, e = s;
    while (e < np) {
        unsigned long long k2 = sorted[e];
        if ((unsigned)(k2 >> 32) != bits) break;
        if ((unsigned)k2 < myidx) rank++;
        e++;
    }
    unsigned row = s + rank;
    if (row >= KPEAKS) return;
    unsigned idx = myidx;
    int z = idx >> 18, y = (idx >> 9) & 511, x = idx & 511;
    float4 ps = psums[sslot[t]];
    float val = __uint_as_float(bits);
    float xloc = ps.y / ps.x, yloc = ps.z / ps.x, zloc = ps.w / ps.x;
    float xr = ((float)x + xloc - (float)(WW - 1) * 0.5f) * 0.1f;
    float yr = ((float)y + yloc - (float)(HH - 1) * 0.5f) * 0.1f;
    float zr = ((float)z + zloc + 0.5f) * 0.02f - 2.0f;
    out[row] = make_float4(xr, yr, zr, val);
    valid[row] = 1.f;
}

extern "C" void kernel_launch(void* const* d_in, const int* in_sizes, int n_in,
                              void* d_out, int out_size, void* d_ws, size_t ws_size,
                              hipStream_t stream) {
    const float* vol = (const float*)d_in[0];
    // d_in[1] = max_peaks scalar (device); fixed at 131072 for this problem.

    char* w = (char*)d_ws;
    unsigned* counters = (unsigned*)w;                                   // 1 KB
    unsigned* hist     = (unsigned*)(w + 1024);                          // 256 KB
    unsigned* cursor   = (unsigned*)(w + 1024 + NBINS * 4);              // 256 KB
    char* w2 = w + 1024 + 2 * NBINS * 4;
    unsigned long long* keys   = (unsigned long long*)w2;                // 2 MB
    unsigned long long* sorted = keys + PEAK_CAP;                        // 2 MB
    unsigned* sslot = (unsigned*)(sorted + PEAK_CAP);                    // 1 MB
    float4*   psums = (float4*)(sslot + PEAK_CAP);                       // 4 MB
    // total ~9.5 MB of ws

    float* out_rows = (float*)d_out;                 // (131072, 4)
    float* valid = out_rows + (size_t)KPEAKS * 4;    // (131072,)

    k_init<<<NBINS / 1024, 1024, 0, stream>>>(counters, hist);
    k_find<<<NVOX / 32768, 1024, 0, stream>>>((const float4*)vol, vol, counters, hist, keys, psums);
    k_scan<<<1, 1024, 0, stream>>>(hist, cursor);
    k_scatter<<<PEAK_CAP / 1024, 1024, 0, stream>>>(counters, keys, cursor, sorted, sslot,
                                                    (float4*)out_rows, valid);
    k_finish<<<PEAK_CAP / 1024, 1024, 0, stream>>>(counters, sorted, sslot, psums,
                                                   (float4*)out_rows, valid);
}

// Round 8
// 254.314 us; speedup vs baseline: 1.2992x; 1.0402x over previous
//
#include <hip/hip_runtime.h>

#define DD 128
#define HH 512
#define WW 512
#define NVOX (DD*HH*WW)          // 33554432
#define THRESHV 0.997f
#define KPEAKS 131072
#define PEAK_CAP (1u<<18)        // 262144 peak slots (expect ~63K)
#define NBINS 65536

// peaks all lie in (0.997, 1.0): float bits have constant upper 16 bits
// 0x3F7F -> low 16 bits monotone in value. bin=(~bits)&0xFFFF so ascending
// bin == descending value. Exact-value ties are COMMON -> tie-fix required.

// ---------------- K0: init scratch (ws is poisoned 0xAA before every call).
__global__ void k_init(unsigned* counters, unsigned* hist) {
    unsigned t = blockIdx.x * 1024u + threadIdx.x;
    if (t < 64) counters[t] = 0u;
    if (t < NBINS) hist[t] = 0u;
}

// ---------------- K1: FUSED stream + verify + centroid. 512 thr x 4096 blk.
// Phase A (R8 change): tile of 8192 voxels (32KB) DMA'd global->LDS via
// __builtin_amdgcn_global_load_lds width=16 (async queue guarantees MLP --
// the compiler serialized register-staged loads in R1/R2/R3/R7, VGPR<=28).
// Threshold scan then reads the tile from LDS (ds_read_b128).
// Phase B: wave per candidate PAIR (R7 body verbatim, 8 waves/block).
// LDS ~38KB -> 4 blocks/CU: one block's verify overlaps another's DMA.
__global__ __launch_bounds__(512, 8)
void k_find(const float4* __restrict__ vol4, const float* __restrict__ vol,
            unsigned* counters, unsigned* hist,
            unsigned long long* keys, float4* psums) {
    __shared__ float4 tile[2048];             // 32KB: the block's voxel tile
    __shared__ unsigned lcnt, pcnt, lbase;
    __shared__ unsigned cidx[384];            // candidate voxel indices (E~25)
    __shared__ unsigned long long lbuf[192];  // surviving peak keys (E~16)
    __shared__ float4 sbuf[192];              // surviving peak centroid sums
    if (threadIdx.x == 0) { lcnt = 0; pcnt = 0; }
    __syncthreads();

    unsigned t = threadIdx.x;
    unsigned lane = t & 63u;
    unsigned w = t >> 6;                      // wave id 0..7 (wave-uniform)
    unsigned blockBase4 = blockIdx.x * 2048u; // float4 units

    // ---- Phase A: async DMA global -> LDS (4 x 16B per thread, all in flight)
#pragma unroll
    for (unsigned i = 0; i < 4; i++) {
        unsigned f = i * 512u + w * 64u;      // wave-uniform float4 slot base
        const float4* gp = vol4 + blockBase4 + f + lane;
        __builtin_amdgcn_global_load_lds(
            (const __attribute__((address_space(1))) unsigned int*)gp,
            (__attribute__((address_space(3))) unsigned int*)(tile + f),
            16, 0, 0);
    }
    __builtin_amdgcn_s_waitcnt(0);
    __syncthreads();

    // ---- threshold scan from LDS
    unsigned m = 0u;
    float4 v[4];
#pragma unroll
    for (unsigned i = 0; i < 4; i++) v[i] = tile[i * 512u + t];
#pragma unroll
    for (unsigned i = 0; i < 4; i++) {
        m |= (v[i].x > THRESHV ? 1u : 0u) << (4 * i);
        m |= (v[i].y > THRESHV ? 1u : 0u) << (4 * i + 1);
        m |= (v[i].z > THRESHV ? 1u : 0u) << (4 * i + 2);
        m |= (v[i].w > THRESHV ? 1u : 0u) << (4 * i + 3);
    }
    while (m) {
        int b = __ffs(m) - 1;
        m &= m - 1u;
        unsigned f4 = blockBase4 + (unsigned)(b >> 2) * 512u + t;
        cidx[atomicAdd(&lcnt, 1u) & 383u] = f4 * 4u + (unsigned)(b & 3);
    }
    __syncthreads();

    // ---- Phase B: verify, 2 candidates per wave iteration (8 waves)
    unsigned n = lcnt > 384u ? 384u : lcnt;
    int dz = (int)lane / 7, dy = (int)lane - dz * 7;   // meaningful for lane<49
    for (unsigned base = w * 2u; base < n; base += 16u) {
        bool has2 = (base + 1u < n);
        unsigned idxA = cidx[base];
        unsigned idxB = has2 ? cidx[base + 1u] : idxA;
        int zA = idxA >> 18, yA = (idxA >> 9) & 511, xA = idxA & 511;
        int zB = idxB >> 18, yB = (idxB >> 9) & 511, xB = idxB & 511;
        int nzA = zA + dz - 3, nyA = yA + dy - 3;
        int nzB = zB + dz - 3, nyB = yB + dy - 3;
        bool rowokA = (lane < 49) && ((unsigned)nzA < DD) && ((unsigned)nyA < HH);
        bool rowokB = (lane < 49) && ((unsigned)nzB < DD) && ((unsigned)nyB < HH);
        size_t rbA = rowokA ? (((size_t)(unsigned)nzA << 18) | ((size_t)(unsigned)nyA << 9))
                            : (((size_t)zA << 18) | ((size_t)yA << 9));
        size_t rbB = rowokB ? (((size_t)(unsigned)nzB << 18) | ((size_t)(unsigned)nyB << 9))
                            : (((size_t)zB << 18) | ((size_t)yB << 9));
        float rvA[7], rvB[7];
        bool intAB = (xA >= 3) && (xA <= WW - 4) && (xB >= 3) && (xB <= WW - 4);
        if (intAB) {
            float4 fA0 = *(const float4*)(vol + rbA + (unsigned)(xA - 3));
            float4 fA1 = *(const float4*)(vol + rbA + (unsigned)(xA + 1));
            float4 fB0 = *(const float4*)(vol + rbB + (unsigned)(xB - 3));
            float4 fB1 = *(const float4*)(vol + rbB + (unsigned)(xB + 1));
            rvA[0] = fA0.x; rvA[1] = fA0.y; rvA[2] = fA0.z; rvA[3] = fA0.w;
            rvA[4] = fA1.x; rvA[5] = fA1.y; rvA[6] = fA1.z;
            rvB[0] = fB0.x; rvB[1] = fB0.y; rvB[2] = fB0.z; rvB[3] = fB0.w;
            rvB[4] = fB1.x; rvB[5] = fB1.y; rvB[6] = fB1.z;
        } else {
            // rare x-edge path (wave-uniform): clamped scalar loads
#pragma unroll
            for (int d = 0; d < 7; d++) {
                int nxA = xA + d - 3;
                bool okA = (unsigned)nxA < WW;
                float va = vol[rbA + (unsigned)(okA ? nxA : xA)];
                rvA[d] = okA ? va : 0.f;
                int nxB = xB + d - 3;
                bool okB = (unsigned)nxB < WW;
                float vb = vol[rbB + (unsigned)(okB ? nxB : xB)];
                rvB[d] = okB ? vb : 0.f;
            }
        }
        if (!rowokA) {
#pragma unroll
            for (int d = 0; d < 7; d++) rvA[d] = 0.f;
        }
        if (!rowokB) {
#pragma unroll
            for (int d = 0; d < 7; d++) rvB[d] = 0.f;
        }
        float centerA = __shfl(rvA[3], 24);
        float centerB = __shfl(rvB[3], 24);

        // ---- candidate A
        {
            bool kill = false;
            float s0r = 0.f, sxr = 0.f;
#pragma unroll
            for (int d = 0; d < 7; d++) {
                kill |= rvA[d] > centerA;
                s0r += rvA[d];
                sxr += rvA[d] * (float)(d - 3);
            }
            if (!__any(kill)) {
                float s0 = s0r, sx = sxr;
                float sy = s0r * (float)(dy - 3);
                float sz = s0r * (float)(dz - 3);
                for (int off = 32; off; off >>= 1) {
                    s0 += __shfl_down(s0, off);
                    sx += __shfl_down(sx, off);
                    sy += __shfl_down(sy, off);
                    sz += __shfl_down(sz, off);
                }
                if (lane == 0) {
                    unsigned bits = __float_as_uint(centerA);
                    atomicAdd(&hist[(~bits) & 0xFFFFu], 1u);
                    unsigned li = atomicAdd(&pcnt, 1u);
                    if (li < 192u) {
                        lbuf[li] = ((unsigned long long)bits << 32) | idxA;
                        sbuf[li] = make_float4(s0, sx, sy, sz);
                    }
                }
            }
        }
        // ---- candidate B
        if (has2) {
            bool kill = false;
            float s0r = 0.f, sxr = 0.f;
#pragma unroll
            for (int d = 0; d < 7; d++) {
                kill |= rvB[d] > centerB;
                s0r += rvB[d];
                sxr += rvB[d] * (float)(d - 3);
            }
            if (!__any(kill)) {
                float s0 = s0r, sx = sxr;
                float sy = s0r * (float)(dy - 3);
                float sz = s0r * (float)(dz - 3);
                for (int off = 32; off; off >>= 1) {
                    s0 += __shfl_down(s0, off);
                    sx += __shfl_down(sx, off);
                    sy += __shfl_down(sy, off);
                    sz += __shfl_down(sz, off);
                }
                if (lane == 0) {
                    unsigned bits = __float_as_uint(centerB);
                    atomicAdd(&hist[(~bits) & 0xFFFFu], 1u);
                    unsigned li = atomicAdd(&pcnt, 1u);
                    if (li < 192u) {
                        lbuf[li] = ((unsigned long long)bits << 32) | idxB;
                        sbuf[li] = make_float4(s0, sx, sy, sz);
                    }
                }
            }
        }
    }
    __syncthreads();
    if (threadIdx.x == 0) lbase = atomicAdd(&counters[1], pcnt);
    __syncthreads();
    unsigned np = pcnt > 192u ? 192u : pcnt;
    for (unsigned i = threadIdx.x; i < np; i += 512u) {
        unsigned p = lbase + i;
        if (p < PEAK_CAP) { keys[p] = lbuf[i]; psums[p] = sbuf[i]; }
    }
}

// ---------------- K2: exclusive prefix sum over 65536 bins (single block),
// uint4-vectorized loads/stores.
__global__ void k_scan(const unsigned* __restrict__ hist, unsigned* cursor) {
    __shared__ unsigned partial[1024];
    int t = threadIdx.x;
    const uint4* h4 = (const uint4*)(hist + t * 64);
    uint4 loc[16];
#pragma unroll
    for (int i = 0; i < 16; i++) loc[i] = h4[i];
    unsigned s = 0;
#pragma unroll
    for (int i = 0; i < 16; i++) s += loc[i].x + loc[i].y + loc[i].z + loc[i].w;
    partial[t] = s;
    __syncthreads();
    for (int off = 1; off < 1024; off <<= 1) {
        unsigned v = (t >= off) ? partial[t - off] : 0u;
        __syncthreads();
        partial[t] += v;
        __syncthreads();
    }
    unsigned run = (t == 0) ? 0u : partial[t - 1];
    uint4* c4 = (uint4*)(cursor + t * 64);
#pragma unroll
    for (int i = 0; i < 16; i++) {
        uint4 h = loc[i]; uint4 o;
        o.x = run; run += h.x;
        o.y = run; run += h.y;
        o.z = run; run += h.z;
        o.w = run; run += h.w;
        c4[i] = o;
    }
}

// ---------------- K3: scatter keys (+slot payload) into descending-value
// order; rows >= np are exactly the all-zero output rows -> zero them here.
__global__ void k_scatter(const unsigned* __restrict__ counters,
                          const unsigned long long* __restrict__ keys,
                          unsigned* cursor, unsigned long long* sorted,
                          unsigned* sslot,
                          float4* __restrict__ out, float* __restrict__ valid) {
    unsigned np = counters[1]; if (np > PEAK_CAP) np = PEAK_CAP;
    unsigned t = blockIdx.x * 1024u + threadIdx.x;
    if (t < np) {
        unsigned long long key = keys[t];
        unsigned bits = (unsigned)(key >> 32);
        unsigned pos = atomicAdd(&cursor[(~bits) & 0xFFFFu], 1u);
        if (pos < PEAK_CAP) { sorted[pos] = key; sslot[pos] = t; }
    } else if (t < KPEAKS) {
        out[t] = make_float4(0.f, 0.f, 0.f, 0.f);
        valid[t] = 0.f;
    }
}

// ---------------- K4: tiefix + output fused. Each scatter position finds its
// tie-corrected row (equal-value runs ordered by ascending voxel idx, per
// lax.top_k) and writes the final output row directly. Bounded by np.
__global__ void k_finish(const unsigned* __restrict__ counters,
                         const unsigned long long* __restrict__ sorted,
                         const unsigned* __restrict__ sslot,
                         const float4* __restrict__ psums,
                         float4* __restrict__ out, float* __restrict__ valid) {
    unsigned np = counters[1]; if (np > PEAK_CAP) np = PEAK_CAP;
    unsigned t = blockIdx.x * 1024u + threadIdx.x;
    if (t >= np) return;
    unsigned long long key = sorted[t];
    unsigned bits = (unsigned)(key >> 32);
    unsigned s = t;
    while (s > 0 && (unsigned)(sorted[s - 1] >> 32) == bits) s--;
    unsigned myidx = (unsigned)key;
    unsigned rank = 0, e = s;
    while (e < np) {
        unsigned long long k2 = sorted[e];
        if ((unsigned)(k2 >> 32) != bits) break;
        if ((unsigned)k2 < myidx) rank++;
        e++;
    }
    unsigned row = s + rank;
    if (row >= KPEAKS) return;
    unsigned idx = myidx;
    int z = idx >> 18, y = (idx >> 9) & 511, x = idx & 511;
    float4 ps = psums[sslot[t]];
    float val = __uint_as_float(bits);
    float xloc = ps.y / ps.x, yloc = ps.z / ps.x, zloc = ps.w / ps.x;
    float xr = ((float)x + xloc - (float)(WW - 1) * 0.5f) * 0.1f;
    float yr = ((float)y + yloc - (float)(HH - 1) * 0.5f) * 0.1f;
    float zr = ((float)z + zloc + 0.5f) * 0.02f - 2.0f;
    out[row] = make_float4(xr, yr, zr, val);
    valid[row] = 1.f;
}

extern "C" void kernel_launch(void* const* d_in, const int* in_sizes, int n_in,
                              void* d_out, int out_size, void* d_ws, size_t ws_size,
                              hipStream_t stream) {
    const float* vol = (const float*)d_in[0];
    // d_in[1] = max_peaks scalar (device); fixed at 131072 for this problem.

    char* w = (char*)d_ws;
    unsigned* counters = (unsigned*)w;                                   // 1 KB
    unsigned* hist     = (unsigned*)(w + 1024);                          // 256 KB
    unsigned* cursor   = (unsigned*)(w + 1024 + NBINS * 4);              // 256 KB
    char* w2 = w + 1024 + 2 * NBINS * 4;
    unsigned long long* keys   = (unsigned long long*)w2;                // 2 MB
    unsigned long long* sorted = keys + PEAK_CAP;                        // 2 MB
    unsigned* sslot = (unsigned*)(sorted + PEAK_CAP);                    // 1 MB
    float4*   psums = (float4*)(sslot + PEAK_CAP);                       // 4 MB
    // total ~9.5 MB of ws

    float* out_rows = (float*)d_out;                 // (131072, 4)
    float* valid = out_rows + (size_t)KPEAKS * 4;    // (131072,)

    k_init<<<NBINS / 1024, 1024, 0, stream>>>(counters, hist);
    k_find<<<NVOX / 8192, 512, 0, stream>>>((const float4*)vol, vol, counters, hist, keys, psums);
    k_scan<<<1, 1024, 0, stream>>>(hist, cursor);
    k_scatter<<<PEAK_CAP / 1024, 1024, 0, stream>>>(counters, keys, cursor, sorted, sslot,
                                                    (float4*)out_rows, valid);
    k_finish<<<PEAK_CAP / 1024, 1024, 0, stream>>>(counters, sorted, sslot, psums,
                                                   (float4*)out_rows, valid);
}